// Round 2
// baseline (105.489 us; speedup 1.0000x reference)
//
#include <hip/hip_runtime.h>

// ColourLoss via telescoped soft-histogram CDF + EMD.
//   cdf_k(x) = sigmoid(2.5*p) - sigmoid(2.5*(p-(k+1))),  p = 255*x  (exact telescope)
// R1: scattered LDS float atomics ~200cyc/wave-instr -> 1 int atomic/pixel.
// R2: QF=16 fine grid (quantization error ~1e-6 on loss vs 7.66e-5 threshold).
// R6: 32-block cdf w/ staggered ds_read_b128 conv; u8-packed plain-store partials.
// R7: diff-histogram (cdf linear in counts) + fused emd; only -0.8us -> cdf math
//   was never ~10us; budget is fill 40.7 (structural) + K1 ~12-14 (atomic pipe
//   floor) + launch gaps ~5-6 + K2' ~2.5.
// R8 (this round): SINGLE fused kernel. 512 blocks x 512 thr (2 blocks/CU).
//   Each block: hist slice -> u8 partials via AGENT-SCOPE (sc0sc1) stores
//   (bypass XCD L2: no wbl2 flush of 32MB dirty poison) -> persistent
//   __device__ counter fetch_add (zero-init module global, NOT poisoned ws;
//   target = next multiple of 64 => iteration/replay-agnostic). Block s==15
//   of each batch spins (relaxed agent loads + s_sleep), one acquire load
//   (L2 inv, cheap), then runs diff-cdf+emd in reused LDS. Deadlock-free:
//   8 waiters << residency (512 blocks all co-resident), workers always exit.
//   Partials fully overwritten every run (re-poison safe).
//   Predict 67.8 -> ~61-64us. Floor left: poison fill + LDS-atomic pipe.
// Red channel skipped: reference computes emd(r_hist, r_hist) == 0 exactly.

#define PADF 64                 // left zero pad floats (covers 16k-48 at k=0)
#define CNTF4 1056              // float4s: (64 + 4096 + 64) / 4
#define SMEM_BYTES 36400        // cnt4[2][1056] | coarse[2][256] | sgt | s0sh | red

__device__ unsigned g_cnt[8 * 16];   // persistent arrival counters, 64B-strided

__device__ __forceinline__ float fsigmoid(float z) {
    return __builtin_amdgcn_rcpf(1.0f + __expf(-z));
}

// block (h, s): hist h = blk>>4 in [0,32) (b=h>>2, ch=1+((h>>1)&1), img_t if
// h&1), slice s = blk&15 of 4096 px. s==15 block also runs batch cdf+emd.
__global__ __launch_bounds__(512, 4) void fused_kernel(
    const float* __restrict__ img, const float* __restrict__ img_t,
    uint4* __restrict__ part, float* __restrict__ out)
{
    __shared__ __align__(16) char smem[SMEM_BYTES];

    const int blk = blockIdx.x;
    const int h   = blk >> 4;
    const int s   = blk & 15;
    const int b   = h >> 2;
    const int ch  = 1 + ((h >> 1) & 1);
    const int tid = threadIdx.x;
    const float* src = (h & 1) ? img_t : img;
    const float4* base = (const float4*)(src + (size_t)(b * 3 + ch) * 65536u
                                             + (size_t)s * 4096u);

    // ---- phase 1: per-block LDS fine histogram (1 ds_add_u32 / pixel) ----
    unsigned* hist = (unsigned*)smem;
    uint4*    h4   = (uint4*)smem;
    h4[tid]       = make_uint4(0u, 0u, 0u, 0u);
    h4[tid + 512] = make_uint4(0u, 0u, 0u, 0u);
    __syncthreads();

    #pragma unroll
    for (int r = 0; r < 2; ++r) {
        const float4 v = base[tid + 512 * r];
        int j0 = (int)(v.x * 4080.0f);
        int j1 = (int)(v.y * 4080.0f);
        int j2 = (int)(v.z * 4080.0f);
        int j3 = (int)(v.w * 4080.0f);
        j0 = j0 < 0 ? 0 : (j0 > 4079 ? 4079 : j0);
        j1 = j1 < 0 ? 0 : (j1 > 4079 ? 4079 : j1);
        j2 = j2 < 0 ? 0 : (j2 > 4079 ? 4079 : j2);
        j3 = j3 < 0 ? 0 : (j3 > 4079 ? 4079 : j3);
        atomicAdd(&hist[j0], 1u);
        atomicAdd(&hist[j1], 1u);
        atomicAdd(&hist[j2], 1u);
        atomicAdd(&hist[j3], 1u);
    }
    __syncthreads();

    // ---- phase 2: u8-pack, publish via agent-scope stores (L2 bypass) ----
    if (tid < 256) {
        const int t = tid;
        const uint4 q0 = h4[4 * t + 0];
        const uint4 q1 = h4[4 * t + 1];
        const uint4 q2 = h4[4 * t + 2];
        const uint4 q3 = h4[4 * t + 3];
        unsigned long long lo, hi;
        lo = (unsigned long long)(q0.x | (q0.y << 8) | (q0.z << 16) | (q0.w << 24))
           | ((unsigned long long)(q1.x | (q1.y << 8) | (q1.z << 16) | (q1.w << 24)) << 32);
        hi = (unsigned long long)(q2.x | (q2.y << 8) | (q2.z << 16) | (q2.w << 24))
           | ((unsigned long long)(q3.x | (q3.y << 8) | (q3.z << 16) | (q3.w << 24)) << 32);
        unsigned long long* w =
            (unsigned long long*)&part[(size_t)blk * 256u + t];
        __hip_atomic_store(w + 0, lo, __ATOMIC_RELAXED, __HIP_MEMORY_SCOPE_AGENT);
        __hip_atomic_store(w + 1, hi, __ATOMIC_RELAXED, __HIP_MEMORY_SCOPE_AGENT);
    }
    __syncthreads();   // vmcnt(0): all publishes at coherent point

    // ---- phase 3: arrival count; batch waiter proceeds to cdf+emd ----
    if (tid == 0) {
        const unsigned o = __hip_atomic_fetch_add(&g_cnt[b * 16], 1u,
                              __ATOMIC_RELAXED, __HIP_MEMORY_SCOPE_AGENT);
        if (s == 15) {
            const unsigned target = (o & ~63u) + 64u;  // this iter ends here
            while (__hip_atomic_load(&g_cnt[b * 16], __ATOMIC_RELAXED,
                                     __HIP_MEMORY_SCOPE_AGENT) < target)
                __builtin_amdgcn_s_sleep(2);
            (void)__hip_atomic_load(&g_cnt[b * 16], __ATOMIC_ACQUIRE,
                                    __HIP_MEMORY_SCOPE_AGENT);  // inv L1/L2
        }
    }
    if (s != 15) return;
    __syncthreads();

    // ---- phase 4 (8 blocks): diff-cdf + emd for batch b ----
    // half 0: green pair h=4b+0/1; half 1: blue pair h=4b+2/3.
    const int half = tid >> 8;
    const int k    = tid & 255;

    float4* cnt4g   = (float4*)smem;                  // [2][CNTF4]
    float4* cntH    = cnt4g + half * CNTF4;
    float*  cn      = (float*)cntH;
    float*  coarse  = (float*)(smem + 33792);         // [2][256]
    float*  coarseH = coarse + half * 256;
    float*  sgt     = (float*)(smem + 35840);         // 128 floats
    float4* sgt4    = (float4*)sgt;
    float*  s0sh    = (float*)(smem + 36352);         // [2]
    float*  red     = (float*)(smem + 36360);         // [8]

    if (tid < 128)
        sgt[tid] = fsigmoid((2.5f / 16.0f) * ((float)tid + 0.5f) - 10.0f);

    // merge 16 img partials (+) and 16 img_t partials (-), u16-SWAR
    const int h0 = b * 4 + half * 2;
    const uint4* p0 = part + (size_t)(h0 * 16) * 256u + k;
    const uint4* p1 = p0 + 16 * 256;   // h0+1 (img_t)

    unsigned pl0 = 0, pl1 = 0, pl2 = 0, pl3 = 0;
    unsigned ph0 = 0, ph1 = 0, ph2 = 0, ph3 = 0;
    unsigned nl0 = 0, nl1 = 0, nl2 = 0, nl3 = 0;
    unsigned nh0 = 0, nh1 = 0, nh2 = 0, nh3 = 0;
    #pragma unroll
    for (int p = 0; p < 16; ++p) {
        const uint4 u = p0[p * 256];
        pl0 += u.x & 0x00FF00FFu; ph0 += (u.x >> 8) & 0x00FF00FFu;
        pl1 += u.y & 0x00FF00FFu; ph1 += (u.y >> 8) & 0x00FF00FFu;
        pl2 += u.z & 0x00FF00FFu; ph2 += (u.z >> 8) & 0x00FF00FFu;
        pl3 += u.w & 0x00FF00FFu; ph3 += (u.w >> 8) & 0x00FF00FFu;
        const uint4 w = p1[p * 256];
        nl0 += w.x & 0x00FF00FFu; nh0 += (w.x >> 8) & 0x00FF00FFu;
        nl1 += w.y & 0x00FF00FFu; nh1 += (w.y >> 8) & 0x00FF00FFu;
        nl2 += w.z & 0x00FF00FFu; nh2 += (w.z >> 8) & 0x00FF00FFu;
        nl3 += w.w & 0x00FF00FFu; nh3 += (w.w >> 8) & 0x00FF00FFu;
    }
    // signed diff counts, fine bins 16k+0..15 (byte j of comp c -> bin 16k+4c+j)
    float f[16];
    f[ 0] = (float)((int)(pl0 & 0xFFFFu) - (int)(nl0 & 0xFFFFu));
    f[ 1] = (float)((int)(ph0 & 0xFFFFu) - (int)(nh0 & 0xFFFFu));
    f[ 2] = (float)((int)(pl0 >> 16)     - (int)(nl0 >> 16));
    f[ 3] = (float)((int)(ph0 >> 16)     - (int)(nh0 >> 16));
    f[ 4] = (float)((int)(pl1 & 0xFFFFu) - (int)(nl1 & 0xFFFFu));
    f[ 5] = (float)((int)(ph1 & 0xFFFFu) - (int)(nh1 & 0xFFFFu));
    f[ 6] = (float)((int)(pl1 >> 16)     - (int)(nl1 >> 16));
    f[ 7] = (float)((int)(ph1 >> 16)     - (int)(nh1 >> 16));
    f[ 8] = (float)((int)(pl2 & 0xFFFFu) - (int)(nl2 & 0xFFFFu));
    f[ 9] = (float)((int)(ph2 & 0xFFFFu) - (int)(nh2 & 0xFFFFu));
    f[10] = (float)((int)(pl2 >> 16)     - (int)(nl2 >> 16));
    f[11] = (float)((int)(ph2 >> 16)     - (int)(nh2 >> 16));
    f[12] = (float)((int)(pl3 & 0xFFFFu) - (int)(nl3 & 0xFFFFu));
    f[13] = (float)((int)(ph3 & 0xFFFFu) - (int)(nh3 & 0xFFFFu));
    f[14] = (float)((int)(pl3 >> 16)     - (int)(nl3 >> 16));
    f[15] = (float)((int)(ph3 >> 16)     - (int)(nh3 >> 16));

    float fs = 0.0f;
    #pragma unroll
    for (int i = 0; i < 16; ++i) fs += f[i];
    coarseH[k] = fs;

    // store 16 diff counts as 4 staggered float4s: bank-group (5k+4r)%8 uniform
    #pragma unroll
    for (int r = 0; r < 4; ++r) {
        const int rr = (r + k) & 3;
        cntH[16 + 4 * k + rr] =
            make_float4(f[4 * rr], f[4 * rr + 1], f[4 * rr + 2], f[4 * rr + 3]);
    }
    if (k < PADF) { cn[k] = 0.0f; cn[PADF + 4096 + k] = 0.0f; }
    __syncthreads();

    // dS0 window: fine bins 0..63 (waves 0 and 4; sigma saturated to 1 above)
    if (k < 64) {
        float s0p = cn[PADF + k] * fsigmoid((2.5f / 16.0f) * ((float)k + 0.5f));
        #pragma unroll
        for (int off = 32; off; off >>= 1) s0p += __shfl_down(s0p, off);
        if (k == 0) s0sh[half] = s0p;
    }
    __syncthreads();

    // inclusive suffix scan of coarse diffs (both halves in lockstep)
    for (int off = 1; off < 256; off <<= 1) {
        const float v = (k + off < 256) ? coarseH[k + off] : 0.0f;
        __syncthreads();
        coarseH[k] += v;
        __syncthreads();
    }

    // conv: 32 staggered b128 dot4s; window floats [16k+16, 16k+144)
    float t = 0.0f;
    #pragma unroll
    for (int c = 0; c < 32; ++c) {
        const int cc = (c + k) & 31;
        const float4 av = cntH[4 * k + 4 + cc];
        const float4 wv = sgt4[cc];
        t += av.x * wv.x + av.y * wv.y + av.z * wv.z + av.w * wv.w;
    }
    const float ones = (k + 5 < 256) ? coarseH[k + 5] : 0.0f;
    const float S0   = s0sh[half] + coarseH[4];
    const float d    = (S0 - t - ones) * (1.0f / 65536.0f);

    // emd: loss_b = sum_k d_g^2 + d_b^2  (k=255 contributes 0)
    float v = (k <= 254) ? d * d : 0.0f;
    #pragma unroll
    for (int off = 32; off; off >>= 1) v += __shfl_down(v, off);
    if ((tid & 63) == 0) red[tid >> 6] = v;
    __syncthreads();
    if (tid == 0)
        out[b] = red[0] + red[1] + red[2] + red[3]
               + red[4] + red[5] + red[6] + red[7];
}

extern "C" void kernel_launch(void* const* d_in, const int* in_sizes, int n_in,
                              void* d_out, int out_size, void* d_ws, size_t ws_size,
                              hipStream_t stream)
{
    const float* img   = (const float*)d_in[0];
    const float* img_t = (const float*)d_in[1];
    float* out = (float*)d_out;

    uint4* part = (uint4*)d_ws;   // 512 blocks * 4 KB = 2 MB (fully overwritten)

    hipLaunchKernelGGL(fused_kernel, dim3(512), dim3(512), 0, stream,
                       img, img_t, part, out);
}

// Round 3
// 68.696 us; speedup vs baseline: 1.5356x; 1.5356x over previous
//
#include <hip/hip_runtime.h>

// ColourLoss via telescoped soft-histogram CDF + EMD.
//   cdf_k(x) = sigmoid(2.5*p) - sigmoid(2.5*(p-(k+1))),  p = 255*x  (exact telescope)
// R1: scattered LDS float atomics ~200cyc/wave-instr -> 1 int atomic/pixel.
// R2: QF=16 fine grid (quantization error ~1e-6 on loss vs 7.66e-5 threshold).
// R7: diff-histogram (cdf linear in counts) + fused emd in K2. 67.8us.
// R8 FAILED (105us): single fused kernel w/ agent-scope handoff. Counters:
//   VALUBusy 1.5%, Occ 4.5%, WRITE 14MB -> sc0sc1 write-through bypassed L2
//   (uncoalesced HBM writes) and the 8 consumer blocks ran a ~35us HBM-latency
//   serial tail on 8 CUs. The second LAUNCH is the cheap full-width barrier +
//   L2-coherent handoff. Reverted to two kernels.
// R9 (this round): probe K1 internals (atomic floor vs contention/latency).
//   (1) dual privatized hists per block: histA<-img, histB<-img_t (halves
//       inter-wave same-bank atomic contention, interleaves two 16KB regions);
//   (2) 512 blocks = 2 blocks/CU, 16 waves/CU to hide load latency;
//   (3) diff formed at K1 (bias +128 u8): partials 2MB->1MB, K2 single stream.
//   Predict: contention/latency real -> 62-64us; atomic floor -> flat ~68
//   (then remaining = fill + reset dispatches => roofline).
// Red channel skipped: reference computes emd(r_hist, r_hist) == 0 exactly.

#define PADF 64                 // left zero pad floats (covers 16k-48 at k=0)
#define CNTF4 1056              // float4s: (64 + 4096 + 64) / 4

__device__ __forceinline__ float fsigmoid(float z) {
    return __builtin_amdgcn_rcpf(1.0f + __expf(-z));
}

// K1: diff fine histogram. 512 blocks x 512 thr; block (pair, s):
// pair = blk>>5 in [0,16): b = pair>>1, ch = 1+(pair&1) (green/blue).
// slice s = blk&31: 2048 px of img AND 2048 px of img_t (1 float4 each/thread).
// histA counts img, histB counts img_t; partial byte = A - B + 128 (exact).
__global__ __launch_bounds__(512) void fine_hist_kernel(
    const float* __restrict__ img, const float* __restrict__ img_t,
    uint4* __restrict__ part)
{
    const int blk  = blockIdx.x;
    const int pair = blk >> 5;
    const int s    = blk & 31;
    const int b    = pair >> 1;
    const int ch   = 1 + (pair & 1);
    const int tid  = threadIdx.x;

    const size_t off = (size_t)(b * 3 + ch) * 65536u + (size_t)s * 2048u;
    const float4* pa = (const float4*)(img   + off);
    const float4* pb = (const float4*)(img_t + off);

    __shared__ unsigned histA[4096];
    __shared__ unsigned histB[4096];
    uint4* zA = (uint4*)histA;
    uint4* zB = (uint4*)histB;
    zA[tid] = make_uint4(0u, 0u, 0u, 0u);
    zA[tid + 512] = make_uint4(0u, 0u, 0u, 0u);
    zB[tid] = make_uint4(0u, 0u, 0u, 0u);
    zB[tid + 512] = make_uint4(0u, 0u, 0u, 0u);

    // issue both input loads before the barrier so they overlap the init
    const float4 va = pa[tid];
    const float4 vb = pb[tid];
    __syncthreads();

    int a0 = (int)(va.x * 4080.0f), a1 = (int)(va.y * 4080.0f);
    int a2 = (int)(va.z * 4080.0f), a3 = (int)(va.w * 4080.0f);
    int b0 = (int)(vb.x * 4080.0f), b1 = (int)(vb.y * 4080.0f);
    int b2 = (int)(vb.z * 4080.0f), b3 = (int)(vb.w * 4080.0f);
    a0 = a0 < 0 ? 0 : (a0 > 4079 ? 4079 : a0);
    a1 = a1 < 0 ? 0 : (a1 > 4079 ? 4079 : a1);
    a2 = a2 < 0 ? 0 : (a2 > 4079 ? 4079 : a2);
    a3 = a3 < 0 ? 0 : (a3 > 4079 ? 4079 : a3);
    b0 = b0 < 0 ? 0 : (b0 > 4079 ? 4079 : b0);
    b1 = b1 < 0 ? 0 : (b1 > 4079 ? 4079 : b1);
    b2 = b2 < 0 ? 0 : (b2 > 4079 ? 4079 : b2);
    b3 = b3 < 0 ? 0 : (b3 > 4079 ? 4079 : b3);
    atomicAdd(&histA[a0], 1u);
    atomicAdd(&histB[b0], 1u);
    atomicAdd(&histA[a1], 1u);
    atomicAdd(&histB[b1], 1u);
    atomicAdd(&histA[a2], 1u);
    atomicAdd(&histB[b2], 1u);
    atomicAdd(&histA[a3], 1u);
    atomicAdd(&histB[b3], 1u);
    __syncthreads();

    // pack 16 biased diff bytes per thread -> one uint4 store (overwrites poison)
    if (tid < 256) {
        const int t = tid;
        uint4 o;
        unsigned w[4];
        #pragma unroll
        for (int q = 0; q < 4; ++q) {
            const uint4 qa = zA[4 * t + q];
            const uint4 qb = zB[4 * t + q];
            const unsigned d0 = (unsigned)((int)qa.x - (int)qb.x + 128) & 255u;
            const unsigned d1 = (unsigned)((int)qa.y - (int)qb.y + 128) & 255u;
            const unsigned d2 = (unsigned)((int)qa.z - (int)qb.z + 128) & 255u;
            const unsigned d3 = (unsigned)((int)qa.w - (int)qb.w + 128) & 255u;
            w[q] = d0 | (d1 << 8) | (d2 << 16) | (d3 << 24);
        }
        o.x = w[0]; o.y = w[1]; o.z = w[2]; o.w = w[3];
        part[(size_t)blk * 256u + t] = o;
    }
}

// K2: fused diff-cdf + emd. 8 blocks x 512 thr; block b, half = tid>>8
// (0: green pair 2b, 1: blue pair 2b+1), k = tid&255.
// Merge 32 biased-u8 slice partials via u16-SWAR: sum_bytes = D + 32*128,
// so f = sum - 4096. Then d_k = (dS0 - dT_k - dsuffix[k+5]) / 65536 and
// loss_b = sum_k d_g^2 + d_b^2, block-reduced to one store (overwrites poison).
__global__ __launch_bounds__(512) void cdf_emd_kernel(
    const uint4* __restrict__ part, float* __restrict__ out)
{
    const int b    = blockIdx.x;   // 0..7
    const int tid  = threadIdx.x;  // 0..511
    const int half = tid >> 8;     // 0 = green pair, 1 = blue pair
    const int k    = tid & 255;    // coarse bin / merge lane

    __shared__ float4 cnt4[2][CNTF4];
    __shared__ float  coarse[2][256];
    __shared__ float4 sgt4[32];
    __shared__ float  s0sh[2];
    __shared__ float  red[8];

    float* cn = (float*)cnt4[half];

    if (tid < 128)
        ((float*)sgt4)[tid] = fsigmoid((2.5f / 16.0f) * ((float)tid + 0.5f) - 10.0f);

    // ---- merge 32 slice partials of pair (biased u8), u16-SWAR ----
    const int pair = b * 2 + half;
    const uint4* p0 = part + (size_t)(pair * 32) * 256u + k;

    unsigned l0 = 0, l1 = 0, l2 = 0, l3 = 0;
    unsigned h0 = 0, h1 = 0, h2 = 0, h3 = 0;
    #pragma unroll
    for (int p = 0; p < 32; ++p) {
        const uint4 u = p0[p * 256];
        l0 += u.x & 0x00FF00FFu; h0 += (u.x >> 8) & 0x00FF00FFu;
        l1 += u.y & 0x00FF00FFu; h1 += (u.y >> 8) & 0x00FF00FFu;
        l2 += u.z & 0x00FF00FFu; h2 += (u.z >> 8) & 0x00FF00FFu;
        l3 += u.w & 0x00FF00FFu; h3 += (u.w >> 8) & 0x00FF00FFu;
    }
    // signed diff counts, fine bins 16k+0..15 (byte j of comp c -> bin 16k+4c+j)
    float f[16];
    f[ 0] = (float)(int)(l0 & 0xFFFFu) - 4096.0f;
    f[ 1] = (float)(int)(h0 & 0xFFFFu) - 4096.0f;
    f[ 2] = (float)(int)(l0 >> 16)     - 4096.0f;
    f[ 3] = (float)(int)(h0 >> 16)     - 4096.0f;
    f[ 4] = (float)(int)(l1 & 0xFFFFu) - 4096.0f;
    f[ 5] = (float)(int)(h1 & 0xFFFFu) - 4096.0f;
    f[ 6] = (float)(int)(l1 >> 16)     - 4096.0f;
    f[ 7] = (float)(int)(h1 >> 16)     - 4096.0f;
    f[ 8] = (float)(int)(l2 & 0xFFFFu) - 4096.0f;
    f[ 9] = (float)(int)(h2 & 0xFFFFu) - 4096.0f;
    f[10] = (float)(int)(l2 >> 16)     - 4096.0f;
    f[11] = (float)(int)(h2 >> 16)     - 4096.0f;
    f[12] = (float)(int)(l3 & 0xFFFFu) - 4096.0f;
    f[13] = (float)(int)(h3 & 0xFFFFu) - 4096.0f;
    f[14] = (float)(int)(l3 >> 16)     - 4096.0f;
    f[15] = (float)(int)(h3 >> 16)     - 4096.0f;

    float fs = 0.0f;
    #pragma unroll
    for (int i = 0; i < 16; ++i) fs += f[i];
    coarse[half][k] = fs;

    // store 16 diff counts as 4 staggered float4s: bank-group (5k+4r)%8 uniform
    #pragma unroll
    for (int r = 0; r < 4; ++r) {
        const int rr = (r + k) & 3;
        cnt4[half][16 + 4 * k + rr] =
            make_float4(f[4 * rr], f[4 * rr + 1], f[4 * rr + 2], f[4 * rr + 3]);
    }
    if (k < PADF) { cn[k] = 0.0f; cn[PADF + 4096 + k] = 0.0f; }
    __syncthreads();

    // dS0 window: fine bins 0..63 (waves 0 and 4; sigma saturated to 1 above)
    if (k < 64) {
        float s0p = cn[PADF + k] * fsigmoid((2.5f / 16.0f) * ((float)k + 0.5f));
        #pragma unroll
        for (int off = 32; off; off >>= 1) s0p += __shfl_down(s0p, off);
        if (k == 0) s0sh[half] = s0p;
    }
    __syncthreads();

    // inclusive suffix scan of coarse diffs (both halves in lockstep)
    for (int off = 1; off < 256; off <<= 1) {
        const float v = (k + off < 256) ? coarse[half][k + off] : 0.0f;
        __syncthreads();
        coarse[half][k] += v;
        __syncthreads();
    }

    // conv: 32 staggered b128 dot4s; window floats [16k+16, 16k+144)
    float t = 0.0f;
    #pragma unroll
    for (int c = 0; c < 32; ++c) {
        const int cc = (c + k) & 31;
        const float4 av = cnt4[half][4 * k + 4 + cc];
        const float4 wv = sgt4[cc];
        t += av.x * wv.x + av.y * wv.y + av.z * wv.z + av.w * wv.w;
    }
    const float ones = (k + 5 < 256) ? coarse[half][k + 5] : 0.0f;
    const float S0   = s0sh[half] + coarse[half][4];
    const float d    = (S0 - t - ones) * (1.0f / 65536.0f);

    // emd: loss_b = sum_k d_g^2 + d_b^2  (k=255 contributes 0)
    float v = (k <= 254) ? d * d : 0.0f;
    #pragma unroll
    for (int off = 32; off; off >>= 1) v += __shfl_down(v, off);
    if ((tid & 63) == 0) red[tid >> 6] = v;
    __syncthreads();
    if (tid == 0)
        out[b] = red[0] + red[1] + red[2] + red[3]
               + red[4] + red[5] + red[6] + red[7];
}

extern "C" void kernel_launch(void* const* d_in, const int* in_sizes, int n_in,
                              void* d_out, int out_size, void* d_ws, size_t ws_size,
                              hipStream_t stream)
{
    const float* img   = (const float*)d_in[0];
    const float* img_t = (const float*)d_in[1];
    float* out = (float*)d_out;

    uint4* part = (uint4*)d_ws;   // 512 blocks * 4 KB = 2 MB (fully overwritten)

    hipLaunchKernelGGL(fine_hist_kernel, dim3(512), dim3(512), 0, stream,
                       img, img_t, part);
    hipLaunchKernelGGL(cdf_emd_kernel, dim3(8), dim3(512), 0, stream,
                       part, out);
}